// Round 6
// baseline (357.443 us; speedup 1.0000x reference)
//
#include <hip/hip_runtime.h>
#include <hip/hip_bf16.h>

typedef unsigned short u16;
typedef unsigned int u32;
typedef short bf16x8 __attribute__((ext_vector_type(8)));
typedef float f32x4 __attribute__((ext_vector_type(4)));

#define MFMA_BF16 __builtin_amdgcn_mfma_f32_16x16x32_bf16

#define B_   2
#define S_   2048
#define E_   2048
#define H_   16
#define KVH_ 4
#define D_   128
#define M_   (B_ * S_)
#define NQKV 3072
#define SCALE_ 0.08838834764831845f  // 1/sqrt(128)

__device__ __forceinline__ float b2f(u16 u) {
    union { u32 i; float f; } x; x.i = ((u32)u) << 16; return x.f;
}
__device__ __forceinline__ u16 f2b(float f) {
    __hip_bfloat16 h = __float2bfloat16(f);
    return *reinterpret_cast<u16*>(&h);
}

// async 16B global->LDS: HW writes lds_base + lane*16  [m97 pattern]
__device__ __forceinline__ void async16(const u16* g, u16* l) {
    __builtin_amdgcn_global_load_lds(
        (const __attribute__((address_space(1))) void*)g,
        (__attribute__((address_space(3))) void*)l, 16, 0, 0);
}

__device__ __forceinline__ uint4 pack8(const float* p) {
    float4 a = *reinterpret_cast<const float4*>(p);
    float4 b = *reinterpret_cast<const float4*>(p + 4);
    union { uint4 v; u16 h[8]; } pk;
    pk.h[0] = f2b(a.x); pk.h[1] = f2b(a.y); pk.h[2] = f2b(a.z); pk.h[3] = f2b(a.w);
    pk.h[4] = f2b(b.x); pk.h[5] = f2b(b.y); pk.h[6] = f2b(b.z); pk.h[7] = f2b(b.w);
    return pk.v;
}

// ---------------------------------------------------------------------------
// f32 -> bf16 bulk convert, up to 4 regions per launch (2048 elems/block).
// ---------------------------------------------------------------------------
__global__ __launch_bounds__(256)
void conv4(const float* __restrict__ s0, u16* __restrict__ d0, int n0,
           const float* __restrict__ s1, u16* __restrict__ d1, int n1,
           const float* __restrict__ s2, u16* __restrict__ d2, int n2,
           const float* __restrict__ s3, u16* __restrict__ d3) {
    int bid = blockIdx.x;
    const float* s; u16* d; size_t base;
    if (bid < n0)                { s = s0; d = d0; base = (size_t)bid * 2048; }
    else if (bid < n0 + n1)      { s = s1; d = d1; base = (size_t)(bid - n0) * 2048; }
    else if (bid < n0 + n1 + n2) { s = s2; d = d2; base = (size_t)(bid - n0 - n1) * 2048; }
    else                         { s = s3; d = d3; base = (size_t)(bid - n0 - n1 - n2) * 2048; }
    size_t i = base + (size_t)threadIdx.x * 8;
    *reinterpret_cast<uint4*>(d + i) = pack8(s + i);
}

// ---------------------------------------------------------------------------
// Shared 128x(NREP*64) GEMM core, BK=64, 8 waves (2M x 4N), double-buffered
// LDS, fragment-major layout (lane-exact async16, conflict-free, PMC-proven
// 0 bank conflicts).  R6: HALF-HEIGHT tile so 2 blocks fit per CU — restores
// cross-block wave overlap (m114): while this block's waves sit at the
// vmcnt+barrier, the co-resident block's waves feed the MFMA pipe.
// Schedule: one stage + counted vmcnt(NREP+2) + one sync-pair per K-tile
// (T3+T4), setprio MFMA clusters (T5); compiler schedules ds_reads.
//   LDS/buffer: A 16 KiB (16 frags) + B NREP*8 frags.
//   per-wave stage: 2 A frags + NREP B frags.
// ---------------------------------------------------------------------------
template <int NREP>
__device__ __forceinline__ void gemm_core(const u16* __restrict__ Ag, int m0,
                                          const u16* const (&Bp)[NREP],
                                          u16* lds, f32x4 (&acc)[4][NREP]) {
    constexpr int BUFSZ = 8192 + NREP * 4096;   // u16 per buffer
    const int tid = threadIdx.x, wave = tid >> 6, lane = tid & 63;
    const int l15 = lane & 15, quad = lane >> 4;
    const int wm = wave & 1, wn = wave >> 1;

    const f32x4 zero4 = {0.f, 0.f, 0.f, 0.f};
    #pragma unroll
    for (int i = 0; i < 4; ++i)
        #pragma unroll
        for (int j = 0; j < NREP; ++j) acc[i][j] = zero4;

    // per-wave A staging pointers: frag tA = wave*2+j, rb=tA>>1, kb=tA&1
    const u16* Ap[2];
    #pragma unroll
    for (int j = 0; j < 2; ++j) {
        int tA = wave * 2 + j;
        Ap[j] = Ag + (size_t)(m0 + (tA >> 1) * 16 + l15) * E_
                   + (tA & 1) * 32 + quad * 8;
    }

    auto stage = [&](int p, int kt) {
        #pragma unroll
        for (int j = 0; j < 2; ++j)
            async16(Ap[j] + kt, &lds[p * BUFSZ + (wave * 2 + j) * 512]);
        #pragma unroll
        for (int j = 0; j < NREP; ++j)
            async16(Bp[j] + kt, &lds[p * BUFSZ + 8192 + (wave * NREP + j) * 512]);
    };

    // prologue: tile 0 -> buf 0 (2+NREP loads in flight)
    stage(0, 0);

    int p = 0;
    for (int kt = 0; kt < E_; kt += 64) {
        __builtin_amdgcn_s_barrier();            // buf p^1 reads (t-1) done
        if (kt + 64 < E_) {
            stage(p ^ 1, kt + 64);               // issue tile t+1
            if constexpr (NREP == 2)
                asm volatile("s_waitcnt vmcnt(4)" ::: "memory");  // t landed
            else
                asm volatile("s_waitcnt vmcnt(5)" ::: "memory");
        } else {
            asm volatile("s_waitcnt vmcnt(0)" ::: "memory");      // drain
        }
        __builtin_amdgcn_sched_barrier(0);
        __builtin_amdgcn_s_barrier();            // tile t visible
        __builtin_amdgcn_sched_barrier(0);

        #pragma unroll
        for (int kb = 0; kb < 2; ++kb) {
            bf16x8 bfr[NREP];
            #pragma unroll
            for (int ni = 0; ni < NREP; ++ni)
                bfr[ni] = *reinterpret_cast<const bf16x8*>(
                    &lds[p * BUFSZ + 8192 +
                         ((((wn * NREP + ni) << 1) | kb) << 9) + lane * 8]);
            bf16x8 af[4];
            #pragma unroll
            for (int i = 0; i < 4; ++i)
                af[i] = *reinterpret_cast<const bf16x8*>(
                    &lds[p * BUFSZ + ((((wm * 4 + i) << 1) | kb) << 9) + lane * 8]);
            __builtin_amdgcn_s_setprio(1);
            #pragma unroll
            for (int mi = 0; mi < 4; ++mi)
                #pragma unroll
                for (int ni = 0; ni < NREP; ++ni)
                    acc[mi][ni] = MFMA_BF16(af[mi], bfr[ni], acc[mi][ni], 0, 0, 0);
            __builtin_amdgcn_s_setprio(0);
        }
        p ^= 1;
    }
}

// XCD-aware bijective chunk swizzle for 32(m) x 16(n) grids, 512 blocks:
// xcd = lin&7 (round-robin dispatch), chunk c = lin>>3 in [0,64).
// 8 XCDs tile the grid as 4n x 2m super-chunks; within an XCD: 4n x 16m.
// Per-XCD per-K-step unique operand slices ~352 KB (fits 4 MiB L2).
__device__ __forceinline__ void xcd_swz512(int lin, int& nIdx, int& mIdx) {
    const int xcd = lin & 7, c = lin >> 3;
    nIdx = (xcd & 3) * 4 + (c & 3);       // [0,16)
    mIdx = (xcd >> 2) * 16 + (c >> 2);    // [0,32)
}

// ---------------------------------------------------------------------------
// Kernel 1: fused QKV gemm_bt + RoPE.  128x192 tile, grid 512 = 2 blocks/CU
// (80 KiB LDS x2 = 160 KiB), 512 thr.  XCD swizzle (T1).  Q/K/V boundary
// straddle handled by per-lane B-row source pointers.
// ---------------------------------------------------------------------------
__global__ __launch_bounds__(512, 4)
void qkv_rope_gemm(const u16* __restrict__ xb, const u16* __restrict__ wqb,
                   const u16* __restrict__ wkb, const u16* __restrict__ wvb,
                   const float* __restrict__ fc, const float* __restrict__ fs,
                   u16* __restrict__ Qr, u16* __restrict__ Kr,
                   u16* __restrict__ Vr) {
    __shared__ __align__(16) u16 lds[2 * (8192 + 12288)];  // 80 KiB
    const int tid = threadIdx.x, wave = tid >> 6, lane = tid & 63;
    const int l15 = lane & 15, quad = lane >> 4;
    int nIdx, mIdx;
    xcd_swz512(blockIdx.y * gridDim.x + blockIdx.x, nIdx, mIdx);
    const int m0 = mIdx * 128, n0 = nIdx * 192;

    // per-lane B staging pointers: frag tB = wave*3+j, row=(tB>>1)*16+l15,
    // kb=tB&1; source selected per global column n (straddle-safe).
    const u16* Bp[3];
    #pragma unroll
    for (int j = 0; j < 3; ++j) {
        int tB = wave * 3 + j;
        int n = n0 + (tB >> 1) * 16 + l15;
        const u16* base; int nl;
        if (n < 2048)      { base = wqb; nl = n; }
        else if (n < 2560) { base = wkb; nl = n - 2048; }
        else               { base = wvb; nl = n - 2560; }
        Bp[j] = base + (size_t)nl * E_ + (tB & 1) * 32 + quad * 8;
    }

    f32x4 acc[4][3];
    gemm_core<3>(xb, m0, Bp, lds, acc);

    const int wm = wave & 1, wn = wave >> 1;
    const int mb_ = m0 + wm * 64, nbase = n0 + wn * 48;
    #pragma unroll
    for (int mi = 0; mi < 4; ++mi)
        #pragma unroll
        for (int ni = 0; ni < 3; ++ni)
            #pragma unroll
            for (int r = 0; r < 4; ++r) {
                int m = mb_ + mi * 16 + quad * 4 + r;   // C/D: row=quad*4+reg
                int n = nbase + ni * 16 + l15;          //      col=lane&15
                int b = m >> 11, s = m & 2047;
                float v = acc[mi][ni][r];
                float other = __shfl_xor(v, 1);
                if (n < 2560) {                          // rope on q and k
                    int d = n & 127;
                    int fi = s * 64 + (d >> 1);
                    float c  = fc[fi];
                    float sn = fs[fi];
                    v = (n & 1) ? (other * sn + v * c) : (v * c - other * sn);
                }
                if (n < 2048) {
                    Qr[((size_t)(b * H_ + (n >> 7)) * S_ + s) * D_ + (n & 127)] = f2b(v);
                } else if (n < 2560) {
                    int kh = (n - 2048) >> 7;
                    Kr[((size_t)(b * KVH_ + kh) * S_ + s) * D_ + (n & 127)] = f2b(v);
                } else {
                    int kh = (n - 2560) >> 7;
                    Vr[((size_t)(b * KVH_ + kh) * S_ + s) * D_ + (n & 127)] = f2b(v);
                }
            }
}

// ---------------------------------------------------------------------------
// Kernel 1.7: V transpose per (b,kvh): Vr[s][d] -> VrT[d][s].
// ---------------------------------------------------------------------------
__global__ __launch_bounds__(256)
void transpose_v(const u16* __restrict__ Vr, u16* __restrict__ VrT) {
    __shared__ u16 t[64][72];
    const int tid = threadIdx.x;
    const int s0 = blockIdx.x * 64, d0 = blockIdx.y * 64, g = blockIdx.z;
    const u16* src = Vr + (size_t)g * S_ * D_;
    u16* dst = VrT + (size_t)g * D_ * S_;
    #pragma unroll
    for (int i = 0; i < 2; ++i) {
        int c = tid + i * 256;
        int r = c >> 3, cc = (c & 7) * 8;
        *reinterpret_cast<uint4*>(&t[r][cc]) =
            *reinterpret_cast<const uint4*>(src + (size_t)(s0 + r) * D_ + d0 + cc);
    }
    __syncthreads();
    #pragma unroll
    for (int i = 0; i < 2; ++i) {
        int c = tid + i * 256;
        int r = c >> 3, cc = (c & 7) * 8;
        u16 tmp[8];
        #pragma unroll
        for (int e = 0; e < 8; ++e) tmp[e] = t[cc + e][r];
        *reinterpret_cast<uint4*>(dst + (size_t)(d0 + r) * S_ + s0 + cc) =
            *reinterpret_cast<const uint4*>(tmp);
    }
}

// ---------------------------------------------------------------------------
// Kernel 2: transposed causal flash attention v4 — SPLIT-KV dual-group.
// [R3: verified, unchanged this round]
// ---------------------------------------------------------------------------
__global__ __launch_bounds__(1024, 4)
void flash2(const u16* __restrict__ Qr, const u16* __restrict__ Kr,
            const u16* __restrict__ VrT, u16* __restrict__ AO) {
    __shared__ __align__(16) u16 Ks[2][2][8192];  // [group][buf] 16 frags
    __shared__ __align__(16) u16 Vs[2][2][8192];
    const int tid = threadIdx.x, wave = tid >> 6, lane = tid & 63;
    const int grp = wave >> 3, gw = wave & 7;     // group, wave-in-group
    const int l15 = lane & 15, quad = lane >> 4;
    const int lin = blockIdx.x;                   // longest-first decode
    const int qt  = 15 - (lin >> 5);
    const int sub = lin & 31;
    const int h = sub & 15, b = sub >> 4;
    const int kvh = h & 3;                        // jnp.tile mapping
    const u16* Qb = Qr + (size_t)(b * H_ + h) * S_ * D_;
    const u16* Kb = Kr + (size_t)(b * KVH_ + kvh) * S_ * D_;
    const u16* Vb = VrT + (size_t)(b * KVH_ + kvh) * D_ * S_;
    const int q0 = qt * 128 + gw * 16;
    const int qg = q0 + l15;                      // this lane's q row

    // Q as B-operand (n=q=l15, k=quad*8+j), register-resident
    bf16x8 bq[4];
    #pragma unroll
    for (int kk = 0; kk < 4; ++kk)
        bq[kk] = *reinterpret_cast<const bf16x8*>(
            Qb + (size_t)qg * D_ + kk * 32 + quad * 8);

    f32x4 o[8];
    const f32x4 zero4 = {0.f, 0.f, 0.f, 0.f};
    #pragma unroll
    for (int i = 0; i < 8; ++i) o[i] = zero4;
    float m_i = -__builtin_inff(), l_i = 0.f;

    // per-wave staging: 2 K frags + 2 V frags of each 64-kv tile (per group).
    const int nt = qt + 1;                        // tiles per group
    const int tbase = grp ? nt : 0;               // this group's first tile
    const int f0 = gw * 2, f1 = gw * 2 + 1;
    const u16* kp0 = Kb + (size_t)tbase * 64 * D_ +
        (size_t)((f0 >> 2) * 16 + l15) * D_ + (f0 & 3) * 32 + quad * 8;
    const u16* kp1 = Kb + (size_t)tbase * 64 * D_ +
        (size_t)((f1 >> 2) * 16 + l15) * D_ + (f1 & 3) * 32 + quad * 8;
    const u16* vp0 = Vb + (size_t)tbase * 64 +
        (size_t)((f0 >> 1) * 16 + l15) * S_ + (f0 & 1) * 32 + quad * 8;
    const u16* vp1 = Vb + (size_t)tbase * 64 +
        (size_t)((f1 >> 1) * 16 + l15) * S_ + (f1 & 1) * 32 + quad * 8;

    // prologue: first tile -> buf 0 (4 loads in flight)
    async16(kp0, &Ks[grp][0][f0 * 512]);
    async16(kp1, &Ks[grp][0][f1 * 512]);
    async16(vp0, &Vs[grp][0][f0 * 512]);
    async16(vp1, &Vs[grp][0][f1 * 512]);

    int p = 0;
    for (int i = 0; i < nt; ++i) {
        __builtin_amdgcn_s_barrier();             // buf p^1 reads (i-1) done
        if (i + 1 < nt) {                         // stage tile i+1 -> buf p^1
            size_t ko = (size_t)(i + 1) * 64 * D_;
            size_t vo = (size_t)(i + 1) * 64;
            async16(kp0 + ko, &Ks[grp][p ^ 1][f0 * 512]);
            async16(kp1 + ko, &Ks[grp][p ^ 1][f1 * 512]);
            async16(vp0 + vo, &Vs[grp][p ^ 1][f0 * 512]);
            async16(vp1 + vo, &Vs[grp][p ^ 1][f1 * 512]);
            asm volatile("s_waitcnt vmcnt(4)" ::: "memory");  // tile i landed
        } else {
            asm volatile("s_waitcnt vmcnt(0)" ::: "memory");  // final drain
        }
        __builtin_amdgcn_sched_barrier(0);
        __builtin_amdgcn_s_barrier();             // tile i visible to group
        __builtin_amdgcn_sched_barrier(0);

        const int kvbase = (tbase + i) * 64;
        if (q0 + 15 >= kvbase) {                  // wave-uniform skip
            // S^T[kv 64][q 16]
            f32x4 st[4];
            #pragma unroll
            for (int kb = 0; kb < 4; ++kb) st[kb] = zero4;
            __builtin_amdgcn_s_setprio(1);
            #pragma unroll
            for (int kk = 0; kk < 4; ++kk)
                #pragma unroll
                for (int kb = 0; kb < 4; ++kb) {
                    bf16x8 ak = *reinterpret_cast<const bf16x8*>(
                        &Ks[grp][p][(((kb << 2) | kk) << 9) + lane * 8]);
                    st[kb] = MFMA_BF16(ak, bq[kk], st[kb], 0, 0, 0);
                }
            __builtin_amdgcn_s_setprio(0);

            // online softmax (lane owns one q col; kv over kb,quad,reg)
            float mx = -__builtin_inff();
            if (kvbase + 63 > q0) {               // diagonal-ish: mask
                #pragma unroll
                for (int kb = 0; kb < 4; ++kb)
                    #pragma unroll
                    for (int r = 0; r < 4; ++r) {
                        float s = st[kb][r] * SCALE_;
                        if (kvbase + kb * 16 + quad * 4 + r > qg)
                            s = -__builtin_inff();
                        st[kb][r] = s;
                        mx = fmaxf(mx, s);
                    }
            } else {
                #pragma unroll
                for (int kb = 0; kb < 4; ++kb)
                    #pragma unroll
                    for (int r = 0; r < 4; ++r) {
                        float s = st[kb][r] * SCALE_;
                        st[kb][r] = s;
                        mx = fmaxf(mx, s);
                    }
            }
            mx = fmaxf(mx, __shfl_xor(mx, 16));
            mx = fmaxf(mx, __shfl_xor(mx, 32));
            // defer-max (T13): skip O-rescale when max didn't grow past THR
            const bool nodefer = !__all(mx - m_i <= 8.0f);
            float mnew = nodefer ? fmaxf(m_i, mx) : m_i;
            float a = __expf(m_i - mnew);         // ==1 on defer path
            float sum = 0.f;
            #pragma unroll
            for (int kb = 0; kb < 4; ++kb)
                #pragma unroll
                for (int r = 0; r < 4; ++r) {
                    float pv = __expf(st[kb][r] - mnew);
                    st[kb][r] = pv;
                    sum += pv;
                }
            sum += __shfl_xor(sum, 16);
            sum += __shfl_xor(sum, 32);
            l_i = l_i * a + sum;
            m_i = mnew;
            if (nodefer) {                        // wave-uniform branch
                #pragma unroll
                for (int mi = 0; mi < 8; ++mi)
                    #pragma unroll
                    for (int r = 0; r < 4; ++r) o[mi][r] *= a;
            }

            // P -> B-frag via packed shuffles; O^T += V^T P^T
            #pragma unroll
            for (int kf = 0; kf < 2; ++kf) {
                u32 pk[4];
                #pragma unroll
                for (int r = 0; r < 4; ++r)
                    pk[r] = (u32)f2b(st[kf * 2 + 0][r]) |
                            ((u32)f2b(st[kf * 2 + 1][r]) << 16);
                bf16x8 bp;
                u16* bh = (u16*)&bp;
                #pragma unroll
                for (int j2 = 0; j2 < 8; ++j2) {
                    int src = ((quad & 1) * 2 + (j2 >> 2)) * 16 + l15;
                    u32 v = __shfl((int)pk[j2 & 3], src);
                    bh[j2] = (lane >= 32) ? (u16)(v >> 16) : (u16)v;
                }
                __builtin_amdgcn_s_setprio(1);
                #pragma unroll
                for (int mi = 0; mi < 8; ++mi) {
                    bf16x8 av = *reinterpret_cast<const bf16x8*>(
                        &Vs[grp][p][(((mi << 1) | kf) << 9) + lane * 8]);
                    o[mi] = MFMA_BF16(av, bp, o[mi], 0, 0, 0);
                }
                __builtin_amdgcn_s_setprio(0);
            }
        }
        p ^= 1;
    }

    // ---- cross-group combine (exact, f32) ----
    float* shf = (float*)&Ks[0][0][0];
    float* shm = (float*)&Vs[0][0][0];
    __syncthreads();                              // all tile reads done
    if (grp == 1) {
        #pragma unroll
        for (int mi = 0; mi < 8; ++mi)
            #pragma unroll
            for (int r = 0; r < 4; ++r)
                shf[((mi << 2) | r) * 512 + gw * 64 + lane] = o[mi][r];
        shm[gw * 64 + lane] = m_i;
        shm[512 + gw * 64 + lane] = l_i;
    }
    __syncthreads();
    if (grp == 0) {
        float m1 = shm[gw * 64 + lane];
        float l1 = shm[512 + gw * 64 + lane];
        float M  = fmaxf(m_i, m1);
        float w0 = __expf(m_i - M), w1 = __expf(m1 - M);  // w1=0 if m1=-inf
        float inv = 1.0f / (w0 * l_i + w1 * l1);
        size_t base = ((size_t)(b * S_ + qg)) * E_ + h * D_;
        #pragma unroll
        for (int mi = 0; mi < 8; ++mi) {
            u16 w[4];
            #pragma unroll
            for (int r = 0; r < 4; ++r) {
                float ov = w0 * o[mi][r] +
                           w1 * shf[((mi << 2) | r) * 512 + gw * 64 + lane];
                w[r] = f2b(ov * inv);
            }
            *reinterpret_cast<uint2*>(AO + base + mi * 16 + quad * 4) =
                *reinterpret_cast<const uint2*>(w);
        }
    }
}

// ---------------------------------------------------------------------------
// Kernel 3: output projection.  128x128 tile, grid 512 = 2 blocks/CU
// (64 KiB LDS x2 = 128 KiB), f32 out.  XCD swizzle + R6 schedule.
// ---------------------------------------------------------------------------
__global__ __launch_bounds__(512, 4)
void out_proj_gemm(const u16* __restrict__ ao, const u16* __restrict__ wob,
                   float* __restrict__ out) {
    __shared__ __align__(16) u16 lds[2 * (8192 + 8192)];  // 64 KiB
    const int tid = threadIdx.x, wave = tid >> 6, lane = tid & 63;
    const int l15 = lane & 15, quad = lane >> 4;
    int nIdx, mIdx;
    xcd_swz512(blockIdx.y * gridDim.x + blockIdx.x, nIdx, mIdx);
    const int m0 = mIdx * 128, n0 = nIdx * 128;

    const u16* Bp[2];
    #pragma unroll
    for (int j = 0; j < 2; ++j) {
        int tB = wave * 2 + j;
        Bp[j] = wob + (size_t)(n0 + (tB >> 1) * 16 + l15) * E_
                    + (tB & 1) * 32 + quad * 8;
    }

    f32x4 acc[4][2];
    gemm_core<2>(ao, m0, Bp, lds, acc);

    const int wm = wave & 1, wn = wave >> 1;
    const int mb_ = m0 + wm * 64, nbase = n0 + wn * 32;
    #pragma unroll
    for (int mi = 0; mi < 4; ++mi)
        #pragma unroll
        for (int ni = 0; ni < 2; ++ni)
            #pragma unroll
            for (int r = 0; r < 4; ++r) {
                int m = mb_ + mi * 16 + quad * 4 + r;
                int n = nbase + ni * 16 + l15;
                out[(size_t)m * E_ + n] = acc[mi][ni][r];
            }
}

// ---------------------------------------------------------------------------
// Workspace (u16 offsets; 50.33 MB, proven-safe):
//   [0,        4194304): wqb (conv->qkv) -> VrT (transpose->flash) -> wob
//   [4194304, 12582912): xb  (conv->qkv) -> AO  (flash->out_proj)
//   [12582912,20971520): Qr
//   [20971520,23068672): Kr
//   [23068672,25165824): Vr
// d_out scratch (rewritten entirely by out_proj at the end):
//   [0, 1048576) u16: wkb   [1048576, 2097152) u16: wvb
// ---------------------------------------------------------------------------
extern "C" void kernel_launch(void* const* d_in, const int* in_sizes, int n_in,
                              void* d_out, int out_size, void* d_ws, size_t ws_size,
                              hipStream_t stream) {
    const float* x  = (const float*)d_in[0];
    const float* wq = (const float*)d_in[1];
    const float* wk = (const float*)d_in[2];
    const float* wv = (const float*)d_in[3];
    const float* wo = (const float*)d_in[4];
    const float* fc = (const float*)d_in[5];
    const float* fs = (const float*)d_in[6];
    float* out = (float*)d_out;

    u16* wqb = (u16*)d_ws;
    u16* xb  = wqb + 4194304;
    u16* Qr  = wqb + 12582912;
    u16* Kr  = wqb + 20971520;
    u16* Vr  = wqb + 23068672;
    u16* VrT = wqb;          // after qkv (wqb dead)
    u16* wob = wqb;          // after flash (VrT dead)
    u16* AO  = xb;           // after qkv (xb dead)
    u16* wkb = (u16*)d_out;  // d_out scratch until out_proj
    u16* wvb = wkb + 1048576;

    conv4<<<7168, 256, 0, stream>>>(x, xb, 4096, wq, wqb, 2048,
                                    wk, wkb, 512, wv, wvb);
    qkv_rope_gemm<<<dim3(NQKV / 192, M_ / 128), 512, 0, stream>>>(
        xb, wqb, wkb, wvb, fc, fs, Qr, Kr, Vr);
    transpose_v<<<dim3(S_ / 64, D_ / 64, B_ * KVH_), 256, 0, stream>>>(Vr, VrT);
    flash2<<<dim3(512), 1024, 0, stream>>>(Qr, Kr, VrT, AO);
    conv4<<<2048, 256, 0, stream>>>(wo, wob, 2048, nullptr, nullptr, 0,
                                    nullptr, nullptr, 0, nullptr, nullptr);
    out_proj_gemm<<<dim3(E_ / 128, M_ / 128), 512, 0, stream>>>(AO, wob, out);
}

// Round 7
// 341.118 us; speedup vs baseline: 1.0479x; 1.0479x over previous
//
#include <hip/hip_runtime.h>
#include <hip/hip_bf16.h>

typedef unsigned short u16;
typedef unsigned int u32;
typedef short bf16x8 __attribute__((ext_vector_type(8)));
typedef float f32x4 __attribute__((ext_vector_type(4)));

#define MFMA_BF16 __builtin_amdgcn_mfma_f32_16x16x32_bf16

#define B_   2
#define S_   2048
#define E_   2048
#define H_   16
#define KVH_ 4
#define D_   128
#define M_   (B_ * S_)
#define NQKV 3072
#define SCALE_ 0.08838834764831845f  // 1/sqrt(128)

__device__ __forceinline__ float b2f(u16 u) {
    union { u32 i; float f; } x; x.i = ((u32)u) << 16; return x.f;
}
__device__ __forceinline__ u16 f2b(float f) {
    __hip_bfloat16 h = __float2bfloat16(f);
    return *reinterpret_cast<u16*>(&h);
}

// async 16B global->LDS: HW writes lds_base + lane*16  [m97 pattern]
__device__ __forceinline__ void async16(const u16* g, u16* l) {
    __builtin_amdgcn_global_load_lds(
        (const __attribute__((address_space(1))) void*)g,
        (__attribute__((address_space(3))) void*)l, 16, 0, 0);
}

__device__ __forceinline__ uint4 pack8(const float* p) {
    float4 a = *reinterpret_cast<const float4*>(p);
    float4 b = *reinterpret_cast<const float4*>(p + 4);
    union { uint4 v; u16 h[8]; } pk;
    pk.h[0] = f2b(a.x); pk.h[1] = f2b(a.y); pk.h[2] = f2b(a.z); pk.h[3] = f2b(a.w);
    pk.h[4] = f2b(b.x); pk.h[5] = f2b(b.y); pk.h[6] = f2b(b.z); pk.h[7] = f2b(b.w);
    return pk.v;
}

// ---------------------------------------------------------------------------
// f32 -> bf16 bulk convert, up to 4 regions per launch (2048 elems/block).
// ---------------------------------------------------------------------------
__global__ __launch_bounds__(256)
void conv4(const float* __restrict__ s0, u16* __restrict__ d0, int n0,
           const float* __restrict__ s1, u16* __restrict__ d1, int n1,
           const float* __restrict__ s2, u16* __restrict__ d2, int n2,
           const float* __restrict__ s3, u16* __restrict__ d3) {
    int bid = blockIdx.x;
    const float* s; u16* d; size_t base;
    if (bid < n0)                { s = s0; d = d0; base = (size_t)bid * 2048; }
    else if (bid < n0 + n1)      { s = s1; d = d1; base = (size_t)(bid - n0) * 2048; }
    else if (bid < n0 + n1 + n2) { s = s2; d = d2; base = (size_t)(bid - n0 - n1) * 2048; }
    else                         { s = s3; d = d3; base = (size_t)(bid - n0 - n1 - n2) * 2048; }
    size_t i = base + (size_t)threadIdx.x * 8;
    *reinterpret_cast<uint4*>(d + i) = pack8(s + i);
}

// ---------------------------------------------------------------------------
// Shared 128x(NREP*64) GEMM core, BK=64, 8 waves (2M x 4N), double-buffered
// LDS, fragment-major layout (lane-exact async16, conflict-free, PMC-proven
// 0 bank conflicts).  2 blocks/CU for cross-block wave overlap (m114).
// Schedule: one stage + counted vmcnt(NREP+2) + one sync-pair per K-tile
// (T3+T4), setprio MFMA clusters (T5).  [R6: verified]
// ---------------------------------------------------------------------------
template <int NREP>
__device__ __forceinline__ void gemm_core(const u16* __restrict__ Ag, int m0,
                                          const u16* const (&Bp)[NREP],
                                          u16* lds, f32x4 (&acc)[4][NREP]) {
    constexpr int BUFSZ = 8192 + NREP * 4096;   // u16 per buffer
    const int tid = threadIdx.x, wave = tid >> 6, lane = tid & 63;
    const int l15 = lane & 15, quad = lane >> 4;
    const int wm = wave & 1, wn = wave >> 1;

    const f32x4 zero4 = {0.f, 0.f, 0.f, 0.f};
    #pragma unroll
    for (int i = 0; i < 4; ++i)
        #pragma unroll
        for (int j = 0; j < NREP; ++j) acc[i][j] = zero4;

    // per-wave A staging pointers: frag tA = wave*2+j, rb=tA>>1, kb=tA&1
    const u16* Ap[2];
    #pragma unroll
    for (int j = 0; j < 2; ++j) {
        int tA = wave * 2 + j;
        Ap[j] = Ag + (size_t)(m0 + (tA >> 1) * 16 + l15) * E_
                   + (tA & 1) * 32 + quad * 8;
    }

    auto stage = [&](int p, int kt) {
        #pragma unroll
        for (int j = 0; j < 2; ++j)
            async16(Ap[j] + kt, &lds[p * BUFSZ + (wave * 2 + j) * 512]);
        #pragma unroll
        for (int j = 0; j < NREP; ++j)
            async16(Bp[j] + kt, &lds[p * BUFSZ + 8192 + (wave * NREP + j) * 512]);
    };

    // prologue: tile 0 -> buf 0 (2+NREP loads in flight)
    stage(0, 0);

    int p = 0;
    for (int kt = 0; kt < E_; kt += 64) {
        __builtin_amdgcn_s_barrier();            // buf p^1 reads (t-1) done
        if (kt + 64 < E_) {
            stage(p ^ 1, kt + 64);               // issue tile t+1
            if constexpr (NREP == 2)
                asm volatile("s_waitcnt vmcnt(4)" ::: "memory");  // t landed
            else
                asm volatile("s_waitcnt vmcnt(5)" ::: "memory");
        } else {
            asm volatile("s_waitcnt vmcnt(0)" ::: "memory");      // drain
        }
        __builtin_amdgcn_sched_barrier(0);
        __builtin_amdgcn_s_barrier();            // tile t visible
        __builtin_amdgcn_sched_barrier(0);

        #pragma unroll
        for (int kb = 0; kb < 2; ++kb) {
            bf16x8 bfr[NREP];
            #pragma unroll
            for (int ni = 0; ni < NREP; ++ni)
                bfr[ni] = *reinterpret_cast<const bf16x8*>(
                    &lds[p * BUFSZ + 8192 +
                         ((((wn * NREP + ni) << 1) | kb) << 9) + lane * 8]);
            bf16x8 af[4];
            #pragma unroll
            for (int i = 0; i < 4; ++i)
                af[i] = *reinterpret_cast<const bf16x8*>(
                    &lds[p * BUFSZ + ((((wm * 4 + i) << 1) | kb) << 9) + lane * 8]);
            __builtin_amdgcn_s_setprio(1);
            #pragma unroll
            for (int mi = 0; mi < 4; ++mi)
                #pragma unroll
                for (int ni = 0; ni < NREP; ++ni)
                    acc[mi][ni] = MFMA_BF16(af[mi], bfr[ni], acc[mi][ni], 0, 0, 0);
            __builtin_amdgcn_s_setprio(0);
        }
        p ^= 1;
    }
}

// XCD-aware bijective chunk swizzle for 32(m) x 16(n) grids, 512 blocks:
// xcd = lin&7 (round-robin dispatch), chunk c = lin>>3 in [0,64).
__device__ __forceinline__ void xcd_swz512(int lin, int& nIdx, int& mIdx) {
    const int xcd = lin & 7, c = lin >> 3;
    nIdx = (xcd & 3) * 4 + (c & 3);       // [0,16)
    mIdx = (xcd >> 2) * 16 + (c >> 2);    // [0,32)
}

// ---------------------------------------------------------------------------
// Kernel 1: fused QKV gemm_bt + RoPE + V-TRANSPOSE.  128x192 tile, grid 512
// = 2 blocks/CU (80 KiB LDS x2), 512 thr.  XCD swizzle (T1).
// R7: V columns write VrT[d][s] DIRECTLY (transpose fused; 4 r-values are
// s-consecutive -> one 8B store).  V path skips the RoPE shuffle (branch is
// wave-uniform per 16-col group; 2560 is a multiple of 16).
// ---------------------------------------------------------------------------
__global__ __launch_bounds__(512, 4)
void qkv_rope_gemm(const u16* __restrict__ xb, const u16* __restrict__ wqb,
                   const u16* __restrict__ wkb, const u16* __restrict__ wvb,
                   const float* __restrict__ fc, const float* __restrict__ fs,
                   u16* __restrict__ Qr, u16* __restrict__ Kr,
                   u16* __restrict__ VrT) {
    __shared__ __align__(16) u16 lds[2 * (8192 + 12288)];  // 80 KiB
    const int tid = threadIdx.x, wave = tid >> 6, lane = tid & 63;
    const int l15 = lane & 15, quad = lane >> 4;
    int nIdx, mIdx;
    xcd_swz512(blockIdx.y * gridDim.x + blockIdx.x, nIdx, mIdx);
    const int m0 = mIdx * 128, n0 = nIdx * 192;

    // per-lane B staging pointers: frag tB = wave*3+j, row=(tB>>1)*16+l15,
    // kb=tB&1; source selected per global column n (straddle-safe).
    const u16* Bp[3];
    #pragma unroll
    for (int j = 0; j < 3; ++j) {
        int tB = wave * 3 + j;
        int n = n0 + (tB >> 1) * 16 + l15;
        const u16* base; int nl;
        if (n < 2048)      { base = wqb; nl = n; }
        else if (n < 2560) { base = wkb; nl = n - 2048; }
        else               { base = wvb; nl = n - 2560; }
        Bp[j] = base + (size_t)nl * E_ + (tB & 1) * 32 + quad * 8;
    }

    f32x4 acc[4][3];
    gemm_core<3>(xb, m0, Bp, lds, acc);

    const int wm = wave & 1, wn = wave >> 1;
    const int mb_ = m0 + wm * 64, nbase = n0 + wn * 48;
    #pragma unroll
    for (int mi = 0; mi < 4; ++mi)
        #pragma unroll
        for (int ni = 0; ni < 3; ++ni) {
            const int ngrp = nbase + ni * 16;     // wave-uniform col group
            if (ngrp >= 2560) {
                // ---- V path: write V^T directly, 4 consecutive s ----
                const int nv = ngrp + l15 - 2560;
                const int kh = nv >> 7, dd = nv & 127;
                const int mr = mb_ + mi * 16 + quad * 4;   // s base (mult 4)
                const int b = mr >> 11, s0 = mr & 2047;
                u16 w[4];
                #pragma unroll
                for (int r = 0; r < 4; ++r) w[r] = f2b(acc[mi][ni][r]);
                *reinterpret_cast<uint2*>(
                    VrT + ((size_t)(b * KVH_ + kh) * D_ + dd) * S_ + s0) =
                    *reinterpret_cast<const uint2*>(w);
            } else {
                // ---- Q/K path: RoPE + scatter (unchanged) ----
                #pragma unroll
                for (int r = 0; r < 4; ++r) {
                    int m = mb_ + mi * 16 + quad * 4 + r;
                    int n = ngrp + l15;
                    int b = m >> 11, s = m & 2047;
                    float v = acc[mi][ni][r];
                    float other = __shfl_xor(v, 1);
                    int d = n & 127;
                    int fi = s * 64 + (d >> 1);
                    float c  = fc[fi];
                    float sn = fs[fi];
                    v = (n & 1) ? (other * sn + v * c) : (v * c - other * sn);
                    if (n < 2048) {
                        Qr[((size_t)(b * H_ + (n >> 7)) * S_ + s) * D_ + d] = f2b(v);
                    } else {
                        int kh = (n - 2048) >> 7;
                        Kr[((size_t)(b * KVH_ + kh) * S_ + s) * D_ + d] = f2b(v);
                    }
                }
            }
        }
}

// ---------------------------------------------------------------------------
// Kernel 2: transposed causal flash attention v4 — SPLIT-KV dual-group.
// [R3: verified, unchanged; VrT base now points at the old Vr slot]
// ---------------------------------------------------------------------------
__global__ __launch_bounds__(1024, 4)
void flash2(const u16* __restrict__ Qr, const u16* __restrict__ Kr,
            const u16* __restrict__ VrT, u16* __restrict__ AO) {
    __shared__ __align__(16) u16 Ks[2][2][8192];  // [group][buf] 16 frags
    __shared__ __align__(16) u16 Vs[2][2][8192];
    const int tid = threadIdx.x, wave = tid >> 6, lane = tid & 63;
    const int grp = wave >> 3, gw = wave & 7;     // group, wave-in-group
    const int l15 = lane & 15, quad = lane >> 4;
    const int lin = blockIdx.x;                   // longest-first decode
    const int qt  = 15 - (lin >> 5);
    const int sub = lin & 31;
    const int h = sub & 15, b = sub >> 4;
    const int kvh = h & 3;                        // jnp.tile mapping
    const u16* Qb = Qr + (size_t)(b * H_ + h) * S_ * D_;
    const u16* Kb = Kr + (size_t)(b * KVH_ + kvh) * S_ * D_;
    const u16* Vb = VrT + (size_t)(b * KVH_ + kvh) * D_ * S_;
    const int q0 = qt * 128 + gw * 16;
    const int qg = q0 + l15;                      // this lane's q row

    // Q as B-operand (n=q=l15, k=quad*8+j), register-resident
    bf16x8 bq[4];
    #pragma unroll
    for (int kk = 0; kk < 4; ++kk)
        bq[kk] = *reinterpret_cast<const bf16x8*>(
            Qb + (size_t)qg * D_ + kk * 32 + quad * 8);

    f32x4 o[8];
    const f32x4 zero4 = {0.f, 0.f, 0.f, 0.f};
    #pragma unroll
    for (int i = 0; i < 8; ++i) o[i] = zero4;
    float m_i = -__builtin_inff(), l_i = 0.f;

    // per-wave staging: 2 K frags + 2 V frags of each 64-kv tile (per group).
    const int nt = qt + 1;                        // tiles per group
    const int tbase = grp ? nt : 0;               // this group's first tile
    const int f0 = gw * 2, f1 = gw * 2 + 1;
    const u16* kp0 = Kb + (size_t)tbase * 64 * D_ +
        (size_t)((f0 >> 2) * 16 + l15) * D_ + (f0 & 3) * 32 + quad * 8;
    const u16* kp1 = Kb + (size_t)tbase * 64 * D_ +
        (size_t)((f1 >> 2) * 16 + l15) * D_ + (f1 & 3) * 32 + quad * 8;
    const u16* vp0 = Vb + (size_t)tbase * 64 +
        (size_t)((f0 >> 1) * 16 + l15) * S_ + (f0 & 1) * 32 + quad * 8;
    const u16* vp1 = Vb + (size_t)tbase * 64 +
        (size_t)((f1 >> 1) * 16 + l15) * S_ + (f1 & 1) * 32 + quad * 8;

    // prologue: first tile -> buf 0 (4 loads in flight)
    async16(kp0, &Ks[grp][0][f0 * 512]);
    async16(kp1, &Ks[grp][0][f1 * 512]);
    async16(vp0, &Vs[grp][0][f0 * 512]);
    async16(vp1, &Vs[grp][0][f1 * 512]);

    int p = 0;
    for (int i = 0; i < nt; ++i) {
        __builtin_amdgcn_s_barrier();             // buf p^1 reads (i-1) done
        if (i + 1 < nt) {                         // stage tile i+1 -> buf p^1
            size_t ko = (size_t)(i + 1) * 64 * D_;
            size_t vo = (size_t)(i + 1) * 64;
            async16(kp0 + ko, &Ks[grp][p ^ 1][f0 * 512]);
            async16(kp1 + ko, &Ks[grp][p ^ 1][f1 * 512]);
            async16(vp0 + vo, &Vs[grp][p ^ 1][f0 * 512]);
            async16(vp1 + vo, &Vs[grp][p ^ 1][f1 * 512]);
            asm volatile("s_waitcnt vmcnt(4)" ::: "memory");  // tile i landed
        } else {
            asm volatile("s_waitcnt vmcnt(0)" ::: "memory");  // final drain
        }
        __builtin_amdgcn_sched_barrier(0);
        __builtin_amdgcn_s_barrier();             // tile i visible to group
        __builtin_amdgcn_sched_barrier(0);

        const int kvbase = (tbase + i) * 64;
        if (q0 + 15 >= kvbase) {                  // wave-uniform skip
            // S^T[kv 64][q 16]
            f32x4 st[4];
            #pragma unroll
            for (int kb = 0; kb < 4; ++kb) st[kb] = zero4;
            __builtin_amdgcn_s_setprio(1);
            #pragma unroll
            for (int kk = 0; kk < 4; ++kk)
                #pragma unroll
                for (int kb = 0; kb < 4; ++kb) {
                    bf16x8 ak = *reinterpret_cast<const bf16x8*>(
                        &Ks[grp][p][(((kb << 2) | kk) << 9) + lane * 8]);
                    st[kb] = MFMA_BF16(ak, bq[kk], st[kb], 0, 0, 0);
                }
            __builtin_amdgcn_s_setprio(0);

            // online softmax (lane owns one q col; kv over kb,quad,reg)
            float mx = -__builtin_inff();
            if (kvbase + 63 > q0) {               // diagonal-ish: mask
                #pragma unroll
                for (int kb = 0; kb < 4; ++kb)
                    #pragma unroll
                    for (int r = 0; r < 4; ++r) {
                        float s = st[kb][r] * SCALE_;
                        if (kvbase + kb * 16 + quad * 4 + r > qg)
                            s = -__builtin_inff();
                        st[kb][r] = s;
                        mx = fmaxf(mx, s);
                    }
            } else {
                #pragma unroll
                for (int kb = 0; kb < 4; ++kb)
                    #pragma unroll
                    for (int r = 0; r < 4; ++r) {
                        float s = st[kb][r] * SCALE_;
                        st[kb][r] = s;
                        mx = fmaxf(mx, s);
                    }
            }
            mx = fmaxf(mx, __shfl_xor(mx, 16));
            mx = fmaxf(mx, __shfl_xor(mx, 32));
            // defer-max (T13): skip O-rescale when max didn't grow past THR
            const bool nodefer = !__all(mx - m_i <= 8.0f);
            float mnew = nodefer ? fmaxf(m_i, mx) : m_i;
            float a = __expf(m_i - mnew);         // ==1 on defer path
            float sum = 0.f;
            #pragma unroll
            for (int kb = 0; kb < 4; ++kb)
                #pragma unroll
                for (int r = 0; r < 4; ++r) {
                    float pv = __expf(st[kb][r] - mnew);
                    st[kb][r] = pv;
                    sum += pv;
                }
            sum += __shfl_xor(sum, 16);
            sum += __shfl_xor(sum, 32);
            l_i = l_i * a + sum;
            m_i = mnew;
            if (nodefer) {                        // wave-uniform branch
                #pragma unroll
                for (int mi = 0; mi < 8; ++mi)
                    #pragma unroll
                    for (int r = 0; r < 4; ++r) o[mi][r] *= a;
            }

            // P -> B-frag via packed shuffles; O^T += V^T P^T
            #pragma unroll
            for (int kf = 0; kf < 2; ++kf) {
                u32 pk[4];
                #pragma unroll
                for (int r = 0; r < 4; ++r)
                    pk[r] = (u32)f2b(st[kf * 2 + 0][r]) |
                            ((u32)f2b(st[kf * 2 + 1][r]) << 16);
                bf16x8 bp;
                u16* bh = (u16*)&bp;
                #pragma unroll
                for (int j2 = 0; j2 < 8; ++j2) {
                    int src = ((quad & 1) * 2 + (j2 >> 2)) * 16 + l15;
                    u32 v = __shfl((int)pk[j2 & 3], src);
                    bh[j2] = (lane >= 32) ? (u16)(v >> 16) : (u16)v;
                }
                __builtin_amdgcn_s_setprio(1);
                #pragma unroll
                for (int mi = 0; mi < 8; ++mi) {
                    bf16x8 av = *reinterpret_cast<const bf16x8*>(
                        &Vs[grp][p][(((mi << 1) | kf) << 9) + lane * 8]);
                    o[mi] = MFMA_BF16(av, bp, o[mi], 0, 0, 0);
                }
                __builtin_amdgcn_s_setprio(0);
            }
        }
        p ^= 1;
    }

    // ---- cross-group combine (exact, f32) ----
    float* shf = (float*)&Ks[0][0][0];
    float* shm = (float*)&Vs[0][0][0];
    __syncthreads();                              // all tile reads done
    if (grp == 1) {
        #pragma unroll
        for (int mi = 0; mi < 8; ++mi)
            #pragma unroll
            for (int r = 0; r < 4; ++r)
                shf[((mi << 2) | r) * 512 + gw * 64 + lane] = o[mi][r];
        shm[gw * 64 + lane] = m_i;
        shm[512 + gw * 64 + lane] = l_i;
    }
    __syncthreads();
    if (grp == 0) {
        float m1 = shm[gw * 64 + lane];
        float l1 = shm[512 + gw * 64 + lane];
        float M  = fmaxf(m_i, m1);
        float w0 = __expf(m_i - M), w1 = __expf(m1 - M);  // w1=0 if m1=-inf
        float inv = 1.0f / (w0 * l_i + w1 * l1);
        size_t base = ((size_t)(b * S_ + qg)) * E_ + h * D_;
        #pragma unroll
        for (int mi = 0; mi < 8; ++mi) {
            u16 w[4];
            #pragma unroll
            for (int r = 0; r < 4; ++r) {
                float ov = w0 * o[mi][r] +
                           w1 * shf[((mi << 2) | r) * 512 + gw * 64 + lane];
                w[r] = f2b(ov * inv);
            }
            *reinterpret_cast<uint2*>(AO + base + mi * 16 + quad * 4) =
                *reinterpret_cast<const uint2*>(w);
        }
    }
}

// ---------------------------------------------------------------------------
// Kernel 3: output projection.  128x128 tile, grid 512 = 2 blocks/CU
// (64 KiB LDS x2), f32 out.  XCD swizzle + R6 schedule.  [unchanged]
// ---------------------------------------------------------------------------
__global__ __launch_bounds__(512, 4)
void out_proj_gemm(const u16* __restrict__ ao, const u16* __restrict__ wob,
                   float* __restrict__ out) {
    __shared__ __align__(16) u16 lds[2 * (8192 + 8192)];  // 64 KiB
    const int tid = threadIdx.x, wave = tid >> 6, lane = tid & 63;
    const int l15 = lane & 15, quad = lane >> 4;
    int nIdx, mIdx;
    xcd_swz512(blockIdx.y * gridDim.x + blockIdx.x, nIdx, mIdx);
    const int m0 = mIdx * 128, n0 = nIdx * 128;

    const u16* Bp[2];
    #pragma unroll
    for (int j = 0; j < 2; ++j) {
        int tB = wave * 2 + j;
        Bp[j] = wob + (size_t)(n0 + (tB >> 1) * 16 + l15) * E_
                    + (tB & 1) * 32 + quad * 8;
    }

    f32x4 acc[4][2];
    gemm_core<2>(ao, m0, Bp, lds, acc);

    const int wm = wave & 1, wn = wave >> 1;
    const int mb_ = m0 + wm * 64, nbase = n0 + wn * 32;
    #pragma unroll
    for (int mi = 0; mi < 4; ++mi)
        #pragma unroll
        for (int ni = 0; ni < 2; ++ni)
            #pragma unroll
            for (int r = 0; r < 4; ++r) {
                int m = mb_ + mi * 16 + quad * 4 + r;
                int n = nbase + ni * 16 + l15;
                out[(size_t)m * E_ + n] = acc[mi][ni][r];
            }
}

// ---------------------------------------------------------------------------
// Workspace (u16 offsets; 50.33 MB, proven-safe).  R7 layout (transpose
// fused; VrT relocated to the old Vr slot so it never aliases wqb):
//   [0,        4194304): wqb (conv->qkv) -> wob (conv2->out_proj)
//   [4194304, 12582912): xb  (conv->qkv) -> AO  (flash->out_proj)
//   [12582912,20971520): Qr
//   [20971520,23068672): Kr
//   [23068672,25165824): VrT (qkv->flash)   [was Vr]
// d_out scratch (rewritten entirely by out_proj at the end):
//   [0, 1048576) u16: wkb   [1048576, 2097152) u16: wvb
// ---------------------------------------------------------------------------
extern "C" void kernel_launch(void* const* d_in, const int* in_sizes, int n_in,
                              void* d_out, int out_size, void* d_ws, size_t ws_size,
                              hipStream_t stream) {
    const float* x  = (const float*)d_in[0];
    const float* wq = (const float*)d_in[1];
    const float* wk = (const float*)d_in[2];
    const float* wv = (const float*)d_in[3];
    const float* wo = (const float*)d_in[4];
    const float* fc = (const float*)d_in[5];
    const float* fs = (const float*)d_in[6];
    float* out = (float*)d_out;

    u16* wqb = (u16*)d_ws;
    u16* xb  = wqb + 4194304;
    u16* Qr  = wqb + 12582912;
    u16* Kr  = wqb + 20971520;
    u16* VrT = wqb + 23068672;   // old Vr slot; exact fit (2x4x128x2048)
    u16* wob = wqb;              // after qkv (wqb dead)
    u16* AO  = xb;               // after qkv (xb dead)
    u16* wkb = (u16*)d_out;      // d_out scratch until out_proj
    u16* wvb = wkb + 1048576;

    conv4<<<7168, 256, 0, stream>>>(x, xb, 4096, wq, wqb, 2048,
                                    wk, wkb, 512, wv, wvb);
    qkv_rope_gemm<<<dim3(NQKV / 192, M_ / 128), 512, 0, stream>>>(
        xb, wqb, wkb, wvb, fc, fs, Qr, Kr, VrT);
    flash2<<<dim3(512), 1024, 0, stream>>>(Qr, Kr, VrT, AO);
    conv4<<<2048, 256, 0, stream>>>(wo, wob, 2048, nullptr, nullptr, 0,
                                    nullptr, nullptr, 0, nullptr, nullptr);
    out_proj_gemm<<<dim3(E_ / 128, M_ / 128), 512, 0, stream>>>(AO, wob, out);
}